// Round 18
// baseline (109.078 us; speedup 1.0000x reference)
//
#include <hip/hip_runtime.h>
#include <cstdint>

typedef __bf16 bf16x8 __attribute__((ext_vector_type(8)));
typedef float f32x4 __attribute__((ext_vector_type(4)));
typedef unsigned short u16;

#define NROWS 4096
#define DIM 512
#define ZROWS 8192
#define DIMP 128     /* projected dims (Walsh coefficients 0..127) */
#define NTILES 64    /* 8192/128 */
#define NBLOCKS 2080 /* 64*65/2 upper-triangular 128x128 tile pairs */
#define GRID3 1040   /* 2080/2 — 2 tiles/block, 4 blocks/CU resident */
#define THR 80.0f    /* certify-skip: d_proj>=80 => d_true>=~79 => sum < 1e-9 */

// ---------------- kernel 1: FWHT projection + norms, FRAGMENT-ORDERED Qf ---------
// (r15 exact, bf16) + ticket reset. Qf: 16-B unit (row, l<16) ->
// Qf[(row>>4)*256 + (l>>2)*64 + (l&3)*16 + (row&15)] — filter reads are
// fully-coalesced 1-KB wave-loads (r13's gather fix, the session's key lever).
__global__ __launch_bounds__(256) void prep_kernel(const float* __restrict__ lbl,
                                                   const float* __restrict__ pred,
                                                   u16* __restrict__ Qf,
                                                   float* __restrict__ xnorm,
                                                   float* __restrict__ pnorm,
                                                   unsigned* __restrict__ ticket) {
    if (blockIdx.x == 0 && threadIdx.x == 0) *ticket = 0u;  // d_ws not re-poisoned
    const int w = threadIdx.x >> 6;
    const int l = threadIdx.x & 63;
    const int row = blockIdx.x * 4 + w;
    const float* src = (row < NROWS) ? (lbl + (size_t)row * DIM)
                                     : (pred + (size_t)(row - NROWS) * DIM);
    const float4 v0 = *(const float4*)(src + l * 8);
    const float4 v1 = *(const float4*)(src + l * 8 + 4);
    float h[8] = {v0.x, v0.y, v0.z, v0.w, v1.x, v1.y, v1.z, v1.w};

    float nrm = 0.f;  // exact f32 norm of the ORIGINAL row (fallback uses it)
#pragma unroll
    for (int j = 0; j < 8; ++j) nrm += h[j] * h[j];
#pragma unroll
    for (int off = 32; off; off >>= 1) nrm += __shfl_xor(nrm, off);
    if (l == 0) xnorm[row] = nrm;

#define BFLY(a, b) { float t = h[a]; h[a] = t + h[b]; h[b] = t - h[b]; }
    BFLY(0, 1) BFLY(2, 3) BFLY(4, 5) BFLY(6, 7)
    BFLY(0, 2) BFLY(1, 3) BFLY(4, 6) BFLY(5, 7)
    BFLY(0, 4) BFLY(1, 5) BFLY(2, 6) BFLY(3, 7)
#undef BFLY
#pragma unroll
    for (int m = 1; m <= 32; m <<= 1) {
#pragma unroll
        for (int j = 0; j < 8; ++j) {
            float p = __shfl_xor(h[j], m);
            h[j] = (l & m) ? (p - h[j]) : (h[j] + p);
        }
    }
    float s = 0.f;
    uint32_t pk[4];
#pragma unroll
    for (int jj = 0; jj < 4; ++jj) {
        uint32_t b0 = __float_as_uint(h[2 * jj] * 0.04419417382f);
        uint32_t b1 = __float_as_uint(h[2 * jj + 1] * 0.04419417382f);
        uint32_t r0 = (b0 + 0x7fffu + ((b0 >> 16) & 1u)) >> 16;
        uint32_t r1 = (b1 + 0x7fffu + ((b1 >> 16) & 1u)) >> 16;
        pk[jj] = r0 | (r1 << 16);
        float fb0 = __uint_as_float(r0 << 16);
        float fb1 = __uint_as_float(r1 << 16);
        s += fb0 * fb0 + fb1 * fb1;
    }
    if (l < 16) {
        const size_t unit = (size_t)(row >> 4) * 256 + (l >> 2) * 64 + (l & 3) * 16 + (row & 15);
        *((uint4*)Qf + unit) = make_uint4(pk[0], pk[1], pk[2], pk[3]);
    }
    s = (l < 16) ? s : 0.f;
#pragma unroll
    for (int off = 32; off; off >>= 1) s += __shfl_xor(s, off);
    if (l == 0) pnorm[row] = s;
}

// ---------------- kernel 2: bf16 register-MFMA filter (r15 body) + fused reduce --
// SINGLE-VARIABLE experiment vs r15 (36.9 us): only the final reduction moved
// in-kernel (ticket + deterministic index-ordered last-block sum). If this is
// ~90us, the ticket tail-serialization is the r17 regression; if ~33us, fp8 was.
__global__ __launch_bounds__(256) void mmd_filter_kernel(const u16* __restrict__ Qf,
                                                         const float* __restrict__ pnorm,
                                                         const float* __restrict__ lbl,
                                                         const float* __restrict__ pred,
                                                         const float* __restrict__ xnorm,
                                                         float* __restrict__ partials,
                                                         unsigned* __restrict__ ticket,
                                                         float* __restrict__ out) {
    __shared__ float red[4];
    __shared__ unsigned isLast;

    const int bid0 = (int)blockIdx.x;
    const int phys = (bid0 & 7) * (GRID3 / 8) + (bid0 >> 3);  // XCD-contiguous
    const int tid = threadIdx.x;
    const int wv = tid >> 6;
    const int l = tid & 63;
    const int wm = wv >> 1, wn = wv & 1;
    const int rl = l & 15;

    int bm = 0, rem = phys * 2;  // block handles triangle ids 2*phys, 2*phys+1
    while (rem >= NTILES - bm) { rem -= NTILES - bm; ++bm; }

    auto baseof = [&](int rowblk) {
        return (const char*)Qf + (size_t)(rowblk >> 4) * 4096 + (size_t)l * 16;
    };

    f32x4 acc[4][4];
#pragma unroll
    for (int m = 0; m < 4; ++m)
#pragma unroll
        for (int n = 0; n < 4; ++n) acc[m][n] = (f32x4){0.f, 0.f, 0.f, 0.f};

    bf16x8 aE[4], bE[4], aO[4], bO[4];
    const char* bA = baseof(bm * 128 + wm * 64);
    const char* bB = baseof((bm + rem) * 128 + wn * 64);

#define LDX(a, b, kc, pA, pB)                                    \
    {                                                            \
        _Pragma("unroll") for (int m = 0; m < 4; ++m) {          \
            a[m] = *(const bf16x8*)((pA) + m * 4096 + (kc) * 1024); \
            b[m] = *(const bf16x8*)((pB) + m * 4096 + (kc) * 1024); \
        }                                                        \
    }
#define MMX(a, b)                                                \
    {                                                            \
        _Pragma("unroll") for (int m = 0; m < 4; ++m)            \
            _Pragma("unroll") for (int n = 0; n < 4; ++n)        \
                acc[m][n] = __builtin_amdgcn_mfma_f32_16x16x32_bf16(a[m], b[n], acc[m][n], 0, 0, 0); \
    }

    LDX(aE, bE, 0, bA, bB);
    float grand = 0.f;

#pragma unroll 1
    for (int k = 0; k < 2; ++k) {
        const int bn = bm + rem;
        const int rowA = bm * 128 + wm * 64;
        const int rowB = bn * 128 + wn * 64;

        LDX(aO, bO, 1, bA, bB); MMX(aE, bE);
        LDX(aE, bE, 2, bA, bB); MMX(aO, bO);
        LDX(aO, bO, 3, bA, bB); MMX(aE, bE);

        int bm2 = bm, rem2 = rem + 1;  // next tile; prefetch chunk 0 into even regs
        if (rem2 >= NTILES - bm2) { rem2 = 0; ++bm2; }
        if (k < 1) {
            bA = baseof(bm2 * 128 + wm * 64);
            bB = baseof((bm2 + rem2) * 128 + wn * 64);
            LDX(aE, bE, 0, bA, bB);
        }
        MMX(aO, bO);

        // ---- epilogue (register-only; certify-skip + rare exact fallback) ----
        float pj[4];
        float4 piv[4];
#pragma unroll
        for (int n = 0; n < 4; ++n) pj[n] = pnorm[rowB + n * 16 + rl];
#pragma unroll
        for (int m = 0; m < 4; ++m)
            piv[m] = *(const float4*)(pnorm + rowA + m * 16 + (l >> 4) * 4);

        float tmin = 1e30f;  // min fragment distance (i==j excluded)
#pragma unroll
        for (int m = 0; m < 4; ++m)
#pragma unroll
            for (int n = 0; n < 4; ++n) {
                const int i0 = rowA + m * 16 + (l >> 4) * 4;
                const int j = rowB + n * 16 + rl;
                const int delta = j - i0;
                float d0 = (piv[m].x + pj[n]) - 2.f * acc[m][n][0];
                float d1 = (piv[m].y + pj[n]) - 2.f * acc[m][n][1];
                float d2 = (piv[m].z + pj[n]) - 2.f * acc[m][n][2];
                float d3 = (piv[m].w + pj[n]) - 2.f * acc[m][n][3];
                d0 = (delta == 0) ? 1e30f : d0;
                d1 = (delta == 1) ? 1e30f : d1;
                d2 = (delta == 2) ? 1e30f : d2;
                d3 = (delta == 3) ? 1e30f : d3;
                tmin = fminf(tmin, fminf(fminf(d0, d1), fminf(d2, d3)));
            }

        if (__ballot(tmin < THR)) {  // ≈never taken (certified); wave-uniform
            float local = 0.f;
#pragma unroll
            for (int m = 0; m < 4; ++m)
#pragma unroll
                for (int n = 0; n < 4; ++n) {
                    float d[4];
                    d[0] = (piv[m].x + pj[n]) - 2.f * acc[m][n][0];
                    d[1] = (piv[m].y + pj[n]) - 2.f * acc[m][n][1];
                    d[2] = (piv[m].z + pj[n]) - 2.f * acc[m][n][2];
                    d[3] = (piv[m].w + pj[n]) - 2.f * acc[m][n][3];
                    const int i0 = rowA + m * 16 + (l >> 4) * 4;
                    const int j = rowB + n * 16 + rl;
#pragma unroll
                    for (int r = 0; r < 4; ++r) {
                        unsigned long long bal = __ballot((d[r] < THR) && (i0 + r != j));
                        while (bal) {  // wave-cooperative exact f32 term
                            const int src = __ffsll((long long)bal) - 1;
                            bal &= bal - 1;
                            const int ii = __shfl(i0 + r, src);
                            const int jj = __shfl(j, src);
                            const float* ri = (ii < NROWS) ? lbl + (size_t)ii * DIM
                                                           : pred + (size_t)(ii - NROWS) * DIM;
                            const float* rj = (jj < NROWS) ? lbl + (size_t)jj * DIM
                                                           : pred + (size_t)(jj - NROWS) * DIM;
                            const float4 a0 = *(const float4*)(ri + l * 8);
                            const float4 a1 = *(const float4*)(ri + l * 8 + 4);
                            const float4 c0 = *(const float4*)(rj + l * 8);
                            const float4 c1 = *(const float4*)(rj + l * 8 + 4);
                            float p = a0.x * c0.x + a0.y * c0.y + a0.z * c0.z + a0.w * c0.w +
                                      a1.x * c1.x + a1.y * c1.y + a1.z * c1.z + a1.w * c1.w;
#pragma unroll
                            for (int off = 32; off; off >>= 1) p += __shfl_xor(p, off);
                            if (l == src) {
                                float dt = xnorm[ii] + xnorm[jj] - 2.f * p;
                                local += exp2f(-0.72134752f * dt);
                            }
                        }
                    }
                }
            const float sgn = ((bm < 32) == (bn < 32)) ? 1.f : -1.f;
            grand += local * sgn * ((bm == bn) ? 1.f : 2.f);
        }
#pragma unroll
        for (int m = 0; m < 4; ++m)
#pragma unroll
            for (int n = 0; n < 4; ++n) acc[m][n] = (f32x4){0.f, 0.f, 0.f, 0.f};
        bm = bm2; rem = rem2;
    }
#undef LDX
#undef MMX

    // ---- block reduce -> partials[phys]; fused deterministic final reduce --------
#pragma unroll
    for (int off = 32; off; off >>= 1) grand += __shfl_xor(grand, off);
    if (l == 0) red[wv] = grand;
    __syncthreads();
    if (tid == 0)
        __hip_atomic_store(partials + phys, red[0] + red[1] + red[2] + red[3],
                           __ATOMIC_RELAXED, __HIP_MEMORY_SCOPE_AGENT);
    __threadfence();
    if (tid == 0) isLast = (atomicAdd(ticket, 1u) == GRID3 - 1) ? 1u : 0u;
    __syncthreads();
    if (isLast) {
        __threadfence();
        float s = 0.f;
        for (int i = tid; i < GRID3; i += 256)  // index order -> deterministic
            s += __hip_atomic_load(partials + i, __ATOMIC_RELAXED, __HIP_MEMORY_SCOPE_AGENT);
#pragma unroll
        for (int off = 32; off; off >>= 1) s += __shfl_xor(s, off);
        if (l == 0) red[wv] = s;
        __syncthreads();
        if (tid == 0)  // + 8192 = Z-diagonal (exp(0)=1, sign +1, exact)
            out[0] = (red[0] + red[1] + red[2] + red[3] + 8192.f) * (1.f / 16777216.f);
    }
}

extern "C" void kernel_launch(void* const* d_in, const int* in_sizes, int n_in,
                              void* d_out, int out_size, void* d_ws, size_t ws_size,
                              hipStream_t stream) {
    const float* lbl = (const float*)d_in[0];
    const float* pred = (const float*)d_in[1];
    u16* Qf = (u16*)d_ws;                                             // 2 MiB
    float* xnorm = (float*)((char*)d_ws + (size_t)ZROWS * DIMP * 2);  // 32 KiB
    float* pnorm = xnorm + ZROWS;                                     // 32 KiB
    float* partials = pnorm + ZROWS;                                  // 4.2 KiB
    unsigned* ticket = (unsigned*)(partials + GRID3);                 // 4 B

    prep_kernel<<<ZROWS / 4, 256, 0, stream>>>(lbl, pred, Qf, xnorm, pnorm, ticket);
    mmd_filter_kernel<<<GRID3, 256, 0, stream>>>(Qf, pnorm, lbl, pred, xnorm,
                                                 partials, ticket, (float*)d_out);
}

// Round 19
// 34.958 us; speedup vs baseline: 3.1203x; 3.1203x over previous
//
#include <hip/hip_runtime.h>
#include <cstdint>

typedef float f32x4 __attribute__((ext_vector_type(4)));

#define NROWS 4096
#define DIM 512
#define ZROWS 8192
#define DIMP 128     /* projected dims (Walsh coefficients 0..127) */
#define NTILES 64    /* 8192/128 */
#define NBLOCKS 2080 /* 64*65/2 upper-triangular 128x128 tile pairs */
#define GRID3 1040   /* 2080/2 — 2 tiles/block, 4 blocks/CU resident */
#define THR 100.0f   /* fp8 certify: d_hat>=100 => d_true>=(10-2)^2=64 => sum<3e-7 */

// ---------------- kernel 1: FWHT + fp8-e4m3 quantize, fragment-ordered Qf8 -------
// Exact Sylvester WHT over 512; rows of H/sqrt(512) orthonormal => Parseval:
// d_proj <= d_true. fp8 e4m3 halves filter operand bytes vs bf16 (same MFMA
// rate). Layout: byte(row,c,kg) = (row>>4)*2048 + c*512 + kg*128 + (row&15)*8,
// so filter lane L reads 8B at blk*2048 + c*512 + L*8 — fully coalesced.
__global__ __launch_bounds__(256) void prep_kernel(const float* __restrict__ lbl,
                                                   const float* __restrict__ pred,
                                                   unsigned char* __restrict__ Qf8,
                                                   float* __restrict__ xnorm,
                                                   float* __restrict__ pnorm) {
    const int w = threadIdx.x >> 6;
    const int l = threadIdx.x & 63;
    const int row = blockIdx.x * 4 + w;
    const float* src = (row < NROWS) ? (lbl + (size_t)row * DIM)
                                     : (pred + (size_t)(row - NROWS) * DIM);
    const float4 v0 = *(const float4*)(src + l * 8);
    const float4 v1 = *(const float4*)(src + l * 8 + 4);
    float h[8] = {v0.x, v0.y, v0.z, v0.w, v1.x, v1.y, v1.z, v1.w};

    float nrm = 0.f;  // exact f32 norm of the ORIGINAL row (fallback uses it)
#pragma unroll
    for (int j = 0; j < 8; ++j) nrm += h[j] * h[j];
#pragma unroll
    for (int off = 32; off; off >>= 1) nrm += __shfl_xor(nrm, off);
    if (l == 0) xnorm[row] = nrm;

#define BFLY(a, b) { float t = h[a]; h[a] = t + h[b]; h[b] = t - h[b]; }
    BFLY(0, 1) BFLY(2, 3) BFLY(4, 5) BFLY(6, 7)
    BFLY(0, 2) BFLY(1, 3) BFLY(4, 6) BFLY(5, 7)
    BFLY(0, 4) BFLY(1, 5) BFLY(2, 6) BFLY(3, 7)
#undef BFLY
#pragma unroll
    for (int m = 1; m <= 32; m <<= 1) {
#pragma unroll
        for (int j = 0; j < 8; ++j) {
            float p = __shfl_xor(h[j], m);
            h[j] = (l & m) ? (p - h[j]) : (h[j] + p);
        }
    }
    // scale by 1/sqrt(512); pack 8 coefs -> 2x4 fp8; pnorm from DEQUANTIZED values
#pragma unroll
    for (int j = 0; j < 8; ++j) h[j] *= 0.04419417382f;
    uint32_t lo = 0, hi = 0;
    lo = __builtin_amdgcn_cvt_pk_fp8_f32(h[0], h[1], lo, false);
    lo = __builtin_amdgcn_cvt_pk_fp8_f32(h[2], h[3], lo, true);
    hi = __builtin_amdgcn_cvt_pk_fp8_f32(h[4], h[5], hi, false);
    hi = __builtin_amdgcn_cvt_pk_fp8_f32(h[6], h[7], hi, true);
    float s = 0.f, b0, b1;  // selector must be a LITERAL (frontend constraint)
    b0 = __builtin_amdgcn_cvt_f32_fp8(lo, 0); b1 = __builtin_amdgcn_cvt_f32_fp8(hi, 0);
    s += b0 * b0 + b1 * b1;
    b0 = __builtin_amdgcn_cvt_f32_fp8(lo, 1); b1 = __builtin_amdgcn_cvt_f32_fp8(hi, 1);
    s += b0 * b0 + b1 * b1;
    b0 = __builtin_amdgcn_cvt_f32_fp8(lo, 2); b1 = __builtin_amdgcn_cvt_f32_fp8(hi, 2);
    s += b0 * b0 + b1 * b1;
    b0 = __builtin_amdgcn_cvt_f32_fp8(lo, 3); b1 = __builtin_amdgcn_cvt_f32_fp8(hi, 3);
    s += b0 * b0 + b1 * b1;
    if (l < 16) {
        const size_t off8 = (size_t)(row >> 4) * 2048 + (l >> 2) * 512 + (l & 3) * 128 + (row & 15) * 8;
        *(uint2*)(Qf8 + off8) = make_uint2(lo, hi);
    }
    s = (l < 16) ? s : 0.f;
#pragma unroll
    for (int off = 32; off; off >>= 1) s += __shfl_xor(s, off);
    if (l == 0) pnorm[row] = s;
}

// ---------------- kernel 2: fp8 register-MFMA certify filter (3-kernel form) -----
// r15 structure exactly (2 tiles/block, cross-tile prefetch, no LDS/barriers,
// partials written with a plain store); ONLY the fragment dtype changed to fp8.
// r18 proved the fused ticket-reduce (NOT fp8) caused r17's regression.
__global__ __launch_bounds__(256) void mmd_filter_kernel(const unsigned char* __restrict__ Qf8,
                                                         const float* __restrict__ pnorm,
                                                         const float* __restrict__ lbl,
                                                         const float* __restrict__ pred,
                                                         const float* __restrict__ xnorm,
                                                         float* __restrict__ partials) {
    __shared__ float red[4];

    const int bid0 = (int)blockIdx.x;
    const int phys = (bid0 & 7) * (GRID3 / 8) + (bid0 >> 3);  // XCD-contiguous
    const int tid = threadIdx.x;
    const int wv = tid >> 6;
    const int l = tid & 63;
    const int wm = wv >> 1, wn = wv & 1;
    const int rl = l & 15;

    int bm = 0, rem = phys * 2;  // block handles triangle ids 2*phys, 2*phys+1
    while (rem >= NTILES - bm) { rem -= NTILES - bm; ++bm; }

    auto baseof = [&](int rowblk) {
        return (const char*)Qf8 + (size_t)(rowblk >> 4) * 2048 + (size_t)l * 8;
    };

    f32x4 acc[4][4];
#pragma unroll
    for (int m = 0; m < 4; ++m)
#pragma unroll
        for (int n = 0; n < 4; ++n) acc[m][n] = (f32x4){0.f, 0.f, 0.f, 0.f};

    long aE[4], bE[4], aO[4], bO[4];
    const char* bA = baseof(bm * 128 + wm * 64);
    const char* bB = baseof((bm + rem) * 128 + wn * 64);

#define LDX(a, b, kc, pA, pB)                                       \
    {                                                               \
        _Pragma("unroll") for (int m = 0; m < 4; ++m) {             \
            a[m] = *(const long*)((pA) + m * 2048 + (kc) * 512);    \
            b[m] = *(const long*)((pB) + m * 2048 + (kc) * 512);    \
        }                                                           \
    }
#define MMX(a, b)                                                   \
    {                                                               \
        _Pragma("unroll") for (int m = 0; m < 4; ++m)               \
            _Pragma("unroll") for (int n = 0; n < 4; ++n)           \
                acc[m][n] = __builtin_amdgcn_mfma_f32_16x16x32_fp8_fp8(a[m], b[n], acc[m][n], 0, 0, 0); \
    }

    LDX(aE, bE, 0, bA, bB);
    float grand = 0.f;

#pragma unroll 1
    for (int k = 0; k < 2; ++k) {
        const int bn = bm + rem;
        const int rowA = bm * 128 + wm * 64;
        const int rowB = bn * 128 + wn * 64;

        LDX(aO, bO, 1, bA, bB); MMX(aE, bE);
        LDX(aE, bE, 2, bA, bB); MMX(aO, bO);
        LDX(aO, bO, 3, bA, bB); MMX(aE, bE);

        int bm2 = bm, rem2 = rem + 1;  // next tile; prefetch chunk 0 into even regs
        if (rem2 >= NTILES - bm2) { rem2 = 0; ++bm2; }
        if (k < 1) {
            bA = baseof(bm2 * 128 + wm * 64);
            bB = baseof((bm2 + rem2) * 128 + wn * 64);
            LDX(aE, bE, 0, bA, bB);
        }
        MMX(aO, bO);

        // ---- epilogue (register-only; certify-skip + rare exact fallback) ----
        float pj[4];
        float4 piv[4];
#pragma unroll
        for (int n = 0; n < 4; ++n) pj[n] = pnorm[rowB + n * 16 + rl];
#pragma unroll
        for (int m = 0; m < 4; ++m)
            piv[m] = *(const float4*)(pnorm + rowA + m * 16 + (l >> 4) * 4);

        float tmin = 1e30f;  // min fragment distance (i==j excluded)
#pragma unroll
        for (int m = 0; m < 4; ++m)
#pragma unroll
            for (int n = 0; n < 4; ++n) {
                const int i0 = rowA + m * 16 + (l >> 4) * 4;
                const int j = rowB + n * 16 + rl;
                const int delta = j - i0;
                float d0 = (piv[m].x + pj[n]) - 2.f * acc[m][n][0];
                float d1 = (piv[m].y + pj[n]) - 2.f * acc[m][n][1];
                float d2 = (piv[m].z + pj[n]) - 2.f * acc[m][n][2];
                float d3 = (piv[m].w + pj[n]) - 2.f * acc[m][n][3];
                d0 = (delta == 0) ? 1e30f : d0;
                d1 = (delta == 1) ? 1e30f : d1;
                d2 = (delta == 2) ? 1e30f : d2;
                d3 = (delta == 3) ? 1e30f : d3;
                tmin = fminf(tmin, fminf(fminf(d0, d1), fminf(d2, d3)));
            }

        if (__ballot(tmin < THR)) {  // rare (~9 pairs expected); wave-uniform
            float local = 0.f;
#pragma unroll
            for (int m = 0; m < 4; ++m)
#pragma unroll
                for (int n = 0; n < 4; ++n) {
                    float d[4];
                    d[0] = (piv[m].x + pj[n]) - 2.f * acc[m][n][0];
                    d[1] = (piv[m].y + pj[n]) - 2.f * acc[m][n][1];
                    d[2] = (piv[m].z + pj[n]) - 2.f * acc[m][n][2];
                    d[3] = (piv[m].w + pj[n]) - 2.f * acc[m][n][3];
                    const int i0 = rowA + m * 16 + (l >> 4) * 4;
                    const int j = rowB + n * 16 + rl;
#pragma unroll
                    for (int r = 0; r < 4; ++r) {
                        unsigned long long bal = __ballot((d[r] < THR) && (i0 + r != j));
                        while (bal) {  // wave-cooperative exact f32 term
                            const int src = __ffsll((long long)bal) - 1;
                            bal &= bal - 1;
                            const int ii = __shfl(i0 + r, src);
                            const int jj = __shfl(j, src);
                            const float* ri = (ii < NROWS) ? lbl + (size_t)ii * DIM
                                                           : pred + (size_t)(ii - NROWS) * DIM;
                            const float* rj = (jj < NROWS) ? lbl + (size_t)jj * DIM
                                                           : pred + (size_t)(jj - NROWS) * DIM;
                            const float4 a0 = *(const float4*)(ri + l * 8);
                            const float4 a1 = *(const float4*)(ri + l * 8 + 4);
                            const float4 c0 = *(const float4*)(rj + l * 8);
                            const float4 c1 = *(const float4*)(rj + l * 8 + 4);
                            float p = a0.x * c0.x + a0.y * c0.y + a0.z * c0.z + a0.w * c0.w +
                                      a1.x * c1.x + a1.y * c1.y + a1.z * c1.z + a1.w * c1.w;
#pragma unroll
                            for (int off = 32; off; off >>= 1) p += __shfl_xor(p, off);
                            if (l == src) {
                                float dt = xnorm[ii] + xnorm[jj] - 2.f * p;
                                local += exp2f(-0.72134752f * dt);
                            }
                        }
                    }
                }
            const float sgn = ((bm < 32) == (bn < 32)) ? 1.f : -1.f;
            grand += local * sgn * ((bm == bn) ? 1.f : 2.f);
        }
#pragma unroll
        for (int m = 0; m < 4; ++m)
#pragma unroll
            for (int n = 0; n < 4; ++n) acc[m][n] = (f32x4){0.f, 0.f, 0.f, 0.f};
        bm = bm2; rem = rem2;
    }
#undef LDX
#undef MMX

    // ---- block reduce (plain store; separate reduce kernel — r18's lesson) ----
#pragma unroll
    for (int off = 32; off; off >>= 1) grand += __shfl_xor(grand, off);
    if (l == 0) red[wv] = grand;
    __syncthreads();
    if (tid == 0) partials[phys] = red[0] + red[1] + red[2] + red[3];
}

// ---------------- kernel 3: deterministic final reduce ---------------------------
__global__ __launch_bounds__(256) void reduce_kernel(const float* __restrict__ partials,
                                                     float* __restrict__ out, int n) {
    __shared__ float red[4];
    float s = 0.f;
    for (int i = threadIdx.x; i < n; i += 256) s += partials[i];
#pragma unroll
    for (int off = 32; off; off >>= 1) s += __shfl_xor(s, off);
    if ((threadIdx.x & 63) == 0) red[threadIdx.x >> 6] = s;
    __syncthreads();
    if (threadIdx.x == 0)  // + 8192 = the Z-diagonal (exp(0)=1, sign +1, exact)
        out[0] = (red[0] + red[1] + red[2] + red[3] + 8192.f) * (1.f / 16777216.f);
}

extern "C" void kernel_launch(void* const* d_in, const int* in_sizes, int n_in,
                              void* d_out, int out_size, void* d_ws, size_t ws_size,
                              hipStream_t stream) {
    const float* lbl = (const float*)d_in[0];
    const float* pred = (const float*)d_in[1];
    unsigned char* Qf8 = (unsigned char*)d_ws;                        // 1 MiB
    float* xnorm = (float*)((char*)d_ws + (size_t)ZROWS * DIMP);      // 32 KiB
    float* pnorm = xnorm + ZROWS;                                     // 32 KiB
    float* partials = pnorm + ZROWS;                                  // 4.2 KiB

    prep_kernel<<<ZROWS / 4, 256, 0, stream>>>(lbl, pred, Qf8, xnorm, pnorm);
    mmd_filter_kernel<<<GRID3, 256, 0, stream>>>(Qf8, pnorm, lbl, pred, xnorm, partials);
    reduce_kernel<<<1, 256, 0, stream>>>(partials, (float*)d_out, GRID3);
}

// Round 20
// 32.044 us; speedup vs baseline: 3.4040x; 1.0909x over previous
//
#include <hip/hip_runtime.h>
#include <cstdint>

typedef float f32x4 __attribute__((ext_vector_type(4)));

#define NROWS 4096
#define DIM 512
#define ZROWS 8192
#define DIMP 128     /* projected dims (Walsh coefficients 0..127) */
#define NTILES 64    /* 8192/128 */
#define NBLOCKS 2080 /* 64*65/2 upper-triangular 128x128 tile pairs */
#define GRID4 1024   /* EXACT residency: 4 blocks/CU x 256 CU; no straggler round */
#define THR 100.0f   /* fp8 certify: d_hat>=100 => d_true>=(10-2)^2=64 => sum<3e-7 */

// ---------------- kernel 1: FWHT + fp8-e4m3 quantize, fragment-ordered Qf8 -------
// Exact Sylvester WHT over 512; rows of H/sqrt(512) orthonormal => Parseval:
// d_proj <= d_true. fp8 e4m3 halves filter operand bytes vs bf16 (same MFMA
// rate). Layout: byte(row,c,kg) = (row>>4)*2048 + c*512 + kg*128 + (row&15)*8,
// so filter lane L reads 8B at blk*2048 + c*512 + L*8 — fully coalesced.
__global__ __launch_bounds__(256) void prep_kernel(const float* __restrict__ lbl,
                                                   const float* __restrict__ pred,
                                                   unsigned char* __restrict__ Qf8,
                                                   float* __restrict__ xnorm,
                                                   float* __restrict__ pnorm) {
    const int w = threadIdx.x >> 6;
    const int l = threadIdx.x & 63;
    const int row = blockIdx.x * 4 + w;
    const float* src = (row < NROWS) ? (lbl + (size_t)row * DIM)
                                     : (pred + (size_t)(row - NROWS) * DIM);
    const float4 v0 = *(const float4*)(src + l * 8);
    const float4 v1 = *(const float4*)(src + l * 8 + 4);
    float h[8] = {v0.x, v0.y, v0.z, v0.w, v1.x, v1.y, v1.z, v1.w};

    float nrm = 0.f;  // exact f32 norm of the ORIGINAL row (fallback uses it)
#pragma unroll
    for (int j = 0; j < 8; ++j) nrm += h[j] * h[j];
#pragma unroll
    for (int off = 32; off; off >>= 1) nrm += __shfl_xor(nrm, off);
    if (l == 0) xnorm[row] = nrm;

#define BFLY(a, b) { float t = h[a]; h[a] = t + h[b]; h[b] = t - h[b]; }
    BFLY(0, 1) BFLY(2, 3) BFLY(4, 5) BFLY(6, 7)
    BFLY(0, 2) BFLY(1, 3) BFLY(4, 6) BFLY(5, 7)
    BFLY(0, 4) BFLY(1, 5) BFLY(2, 6) BFLY(3, 7)
#undef BFLY
#pragma unroll
    for (int m = 1; m <= 32; m <<= 1) {
#pragma unroll
        for (int j = 0; j < 8; ++j) {
            float p = __shfl_xor(h[j], m);
            h[j] = (l & m) ? (p - h[j]) : (h[j] + p);
        }
    }
    // scale by 1/sqrt(512); pack 8 coefs -> 2x4 fp8; pnorm from DEQUANTIZED values
#pragma unroll
    for (int j = 0; j < 8; ++j) h[j] *= 0.04419417382f;
    uint32_t lo = 0, hi = 0;
    lo = __builtin_amdgcn_cvt_pk_fp8_f32(h[0], h[1], lo, false);
    lo = __builtin_amdgcn_cvt_pk_fp8_f32(h[2], h[3], lo, true);
    hi = __builtin_amdgcn_cvt_pk_fp8_f32(h[4], h[5], hi, false);
    hi = __builtin_amdgcn_cvt_pk_fp8_f32(h[6], h[7], hi, true);
    float s = 0.f, b0, b1;  // selector must be a LITERAL (frontend constraint)
    b0 = __builtin_amdgcn_cvt_f32_fp8(lo, 0); b1 = __builtin_amdgcn_cvt_f32_fp8(hi, 0);
    s += b0 * b0 + b1 * b1;
    b0 = __builtin_amdgcn_cvt_f32_fp8(lo, 1); b1 = __builtin_amdgcn_cvt_f32_fp8(hi, 1);
    s += b0 * b0 + b1 * b1;
    b0 = __builtin_amdgcn_cvt_f32_fp8(lo, 2); b1 = __builtin_amdgcn_cvt_f32_fp8(hi, 2);
    s += b0 * b0 + b1 * b1;
    b0 = __builtin_amdgcn_cvt_f32_fp8(lo, 3); b1 = __builtin_amdgcn_cvt_f32_fp8(hi, 3);
    s += b0 * b0 + b1 * b1;
    if (l < 16) {
        const size_t off8 = (size_t)(row >> 4) * 2048 + (l >> 2) * 512 + (l & 3) * 128 + (row & 15) * 8;
        *(uint2*)(Qf8 + off8) = make_uint2(lo, hi);
    }
    s = (l < 16) ? s : 0.f;
#pragma unroll
    for (int off = 32; off; off >>= 1) s += __shfl_xor(s, off);
    if (l == 0) pnorm[row] = s;
}

// ---------------- kernel 2: fp8 certify filter, exact-residency grid -------------
// r19 body; GRID 1040->1024 (single variable). Blocks 0..1023 take consecutive
// tile ids (2b, 2b+1); blocks 0..31 absorb the 32 leftover ids (2048+b) as a
// third tile — concurrent with everyone, instead of r19's 16-block second round
// (1040 > 1024 co-resident at VGPR~128 => straggler round appended one full
// block-duration to the kernel).
__global__ __launch_bounds__(256) void mmd_filter_kernel(const unsigned char* __restrict__ Qf8,
                                                         const float* __restrict__ pnorm,
                                                         const float* __restrict__ lbl,
                                                         const float* __restrict__ pred,
                                                         const float* __restrict__ xnorm,
                                                         float* __restrict__ partials) {
    __shared__ float red[4];

    const int bid0 = (int)blockIdx.x;
    const int phys = (bid0 & 7) * (GRID4 / 8) + (bid0 >> 3);  // XCD-contiguous
    const int tid = threadIdx.x;
    const int wv = tid >> 6;
    const int l = tid & 63;
    const int wm = wv >> 1, wn = wv & 1;
    const int rl = l & 15;

    auto DEC = [&](int id, int& bm, int& bn) {
        int b = 0, r = id;
        while (r >= NTILES - b) { r -= NTILES - b; ++b; }
        bm = b; bn = b + r;
    };
    int bm0, bn0, bm1, bn1, bm2 = 0, bn2 = 0;
    DEC(phys * 2, bm0, bn0);
    DEC(phys * 2 + 1, bm1, bn1);
    const int nT = (phys < NBLOCKS - 2 * GRID4) ? 3 : 2;  // first 32 blocks take 3
    if (nT == 3) DEC(2 * GRID4 + phys, bm2, bn2);

    auto baseof = [&](int rowblk) {
        return (const char*)Qf8 + (size_t)(rowblk >> 4) * 2048 + (size_t)l * 8;
    };

    f32x4 acc[4][4];
#pragma unroll
    for (int m = 0; m < 4; ++m)
#pragma unroll
        for (int n = 0; n < 4; ++n) acc[m][n] = (f32x4){0.f, 0.f, 0.f, 0.f};

    long aE[4], bE[4], aO[4], bO[4];
    const char* bA = baseof(bm0 * 128 + wm * 64);
    const char* bB = baseof(bn0 * 128 + wn * 64);

#define LDX(a, b, kc, pA, pB)                                       \
    {                                                               \
        _Pragma("unroll") for (int m = 0; m < 4; ++m) {             \
            a[m] = *(const long*)((pA) + m * 2048 + (kc) * 512);    \
            b[m] = *(const long*)((pB) + m * 2048 + (kc) * 512);    \
        }                                                           \
    }
#define MMX(a, b)                                                   \
    {                                                               \
        _Pragma("unroll") for (int m = 0; m < 4; ++m)               \
            _Pragma("unroll") for (int n = 0; n < 4; ++n)           \
                acc[m][n] = __builtin_amdgcn_mfma_f32_16x16x32_fp8_fp8(a[m], b[n], acc[m][n], 0, 0, 0); \
    }

    LDX(aE, bE, 0, bA, bB);
    float grand = 0.f;

#pragma unroll 1
    for (int k = 0; k < nT; ++k) {
        const int bmT = (k == 0) ? bm0 : ((k == 1) ? bm1 : bm2);
        const int bnT = (k == 0) ? bn0 : ((k == 1) ? bn1 : bn2);
        const int rowA = bmT * 128 + wm * 64;
        const int rowB = bnT * 128 + wn * 64;

        LDX(aO, bO, 1, bA, bB); MMX(aE, bE);
        LDX(aE, bE, 2, bA, bB); MMX(aO, bO);
        LDX(aO, bO, 3, bA, bB); MMX(aE, bE);

        if (k + 1 < nT) {  // prefetch next tile's chunk 0 into freed even regs
            const int bmN = (k == 0) ? bm1 : bm2;
            const int bnN = (k == 0) ? bn1 : bn2;
            bA = baseof(bmN * 128 + wm * 64);
            bB = baseof(bnN * 128 + wn * 64);
            LDX(aE, bE, 0, bA, bB);
        }
        MMX(aO, bO);

        // ---- epilogue (register-only; certify-skip + rare exact fallback) ----
        float pj[4];
        float4 piv[4];
#pragma unroll
        for (int n = 0; n < 4; ++n) pj[n] = pnorm[rowB + n * 16 + rl];
#pragma unroll
        for (int m = 0; m < 4; ++m)
            piv[m] = *(const float4*)(pnorm + rowA + m * 16 + (l >> 4) * 4);

        float tmin = 1e30f;  // min fragment distance (i==j excluded)
#pragma unroll
        for (int m = 0; m < 4; ++m)
#pragma unroll
            for (int n = 0; n < 4; ++n) {
                const int i0 = rowA + m * 16 + (l >> 4) * 4;
                const int j = rowB + n * 16 + rl;
                const int delta = j - i0;
                float d0 = (piv[m].x + pj[n]) - 2.f * acc[m][n][0];
                float d1 = (piv[m].y + pj[n]) - 2.f * acc[m][n][1];
                float d2 = (piv[m].z + pj[n]) - 2.f * acc[m][n][2];
                float d3 = (piv[m].w + pj[n]) - 2.f * acc[m][n][3];
                d0 = (delta == 0) ? 1e30f : d0;
                d1 = (delta == 1) ? 1e30f : d1;
                d2 = (delta == 2) ? 1e30f : d2;
                d3 = (delta == 3) ? 1e30f : d3;
                tmin = fminf(tmin, fminf(fminf(d0, d1), fminf(d2, d3)));
            }

        if (__ballot(tmin < THR)) {  // rare (~9 pairs expected); wave-uniform
            float local = 0.f;
#pragma unroll
            for (int m = 0; m < 4; ++m)
#pragma unroll
                for (int n = 0; n < 4; ++n) {
                    float d[4];
                    d[0] = (piv[m].x + pj[n]) - 2.f * acc[m][n][0];
                    d[1] = (piv[m].y + pj[n]) - 2.f * acc[m][n][1];
                    d[2] = (piv[m].z + pj[n]) - 2.f * acc[m][n][2];
                    d[3] = (piv[m].w + pj[n]) - 2.f * acc[m][n][3];
                    const int i0 = rowA + m * 16 + (l >> 4) * 4;
                    const int j = rowB + n * 16 + rl;
#pragma unroll
                    for (int r = 0; r < 4; ++r) {
                        unsigned long long bal = __ballot((d[r] < THR) && (i0 + r != j));
                        while (bal) {  // wave-cooperative exact f32 term
                            const int src = __ffsll((long long)bal) - 1;
                            bal &= bal - 1;
                            const int ii = __shfl(i0 + r, src);
                            const int jj = __shfl(j, src);
                            const float* ri = (ii < NROWS) ? lbl + (size_t)ii * DIM
                                                           : pred + (size_t)(ii - NROWS) * DIM;
                            const float* rj = (jj < NROWS) ? lbl + (size_t)jj * DIM
                                                           : pred + (size_t)(jj - NROWS) * DIM;
                            const float4 a0 = *(const float4*)(ri + l * 8);
                            const float4 a1 = *(const float4*)(ri + l * 8 + 4);
                            const float4 c0 = *(const float4*)(rj + l * 8);
                            const float4 c1 = *(const float4*)(rj + l * 8 + 4);
                            float p = a0.x * c0.x + a0.y * c0.y + a0.z * c0.z + a0.w * c0.w +
                                      a1.x * c1.x + a1.y * c1.y + a1.z * c1.z + a1.w * c1.w;
#pragma unroll
                            for (int off = 32; off; off >>= 1) p += __shfl_xor(p, off);
                            if (l == src) {
                                float dt = xnorm[ii] + xnorm[jj] - 2.f * p;
                                local += exp2f(-0.72134752f * dt);
                            }
                        }
                    }
                }
            const float sgn = ((bmT < 32) == (bnT < 32)) ? 1.f : -1.f;
            grand += local * sgn * ((bmT == bnT) ? 1.f : 2.f);
        }
#pragma unroll
        for (int m = 0; m < 4; ++m)
#pragma unroll
            for (int n = 0; n < 4; ++n) acc[m][n] = (f32x4){0.f, 0.f, 0.f, 0.f};
    }
#undef LDX
#undef MMX

    // ---- block reduce (plain store; separate reduce kernel — r18's lesson) ----
#pragma unroll
    for (int off = 32; off; off >>= 1) grand += __shfl_xor(grand, off);
    if (l == 0) red[wv] = grand;
    __syncthreads();
    if (tid == 0) partials[phys] = red[0] + red[1] + red[2] + red[3];
}

// ---------------- kernel 3: deterministic final reduce ---------------------------
__global__ __launch_bounds__(256) void reduce_kernel(const float* __restrict__ partials,
                                                     float* __restrict__ out, int n) {
    __shared__ float red[4];
    float s = 0.f;
    for (int i = threadIdx.x; i < n; i += 256) s += partials[i];
#pragma unroll
    for (int off = 32; off; off >>= 1) s += __shfl_xor(s, off);
    if ((threadIdx.x & 63) == 0) red[threadIdx.x >> 6] = s;
    __syncthreads();
    if (threadIdx.x == 0)  // + 8192 = the Z-diagonal (exp(0)=1, sign +1, exact)
        out[0] = (red[0] + red[1] + red[2] + red[3] + 8192.f) * (1.f / 16777216.f);
}

extern "C" void kernel_launch(void* const* d_in, const int* in_sizes, int n_in,
                              void* d_out, int out_size, void* d_ws, size_t ws_size,
                              hipStream_t stream) {
    const float* lbl = (const float*)d_in[0];
    const float* pred = (const float*)d_in[1];
    unsigned char* Qf8 = (unsigned char*)d_ws;                        // 1 MiB
    float* xnorm = (float*)((char*)d_ws + (size_t)ZROWS * DIMP);      // 32 KiB
    float* pnorm = xnorm + ZROWS;                                     // 32 KiB
    float* partials = pnorm + ZROWS;                                  // 4 KiB

    prep_kernel<<<ZROWS / 4, 256, 0, stream>>>(lbl, pred, Qf8, xnorm, pnorm);
    mmd_filter_kernel<<<GRID4, 256, 0, stream>>>(Qf8, pnorm, lbl, pred, xnorm, partials);
    reduce_kernel<<<1, 256, 0, stream>>>(partials, (float*)d_out, GRID4);
}

// Round 21
// 30.829 us; speedup vs baseline: 3.5381x; 1.0394x over previous
//
#include <hip/hip_runtime.h>
#include <cstdint>

typedef float f32x4 __attribute__((ext_vector_type(4)));

#define NROWS 4096
#define DIM 512
#define ZROWS 8192
#define DIMP 128     /* projected dims (Walsh coefficients 0..127) */
#define NTILES 64    /* 8192/128 */
#define NBLOCKS 2080 /* 64*65/2 upper-triangular 128x128 tile pairs */
#define GRID4 1024   /* EXACT residency: 4 blocks/CU x 256 CU */
#define THR 100.0f   /* fp8 certify: d_hat>=100 => d_true>=(10-2)^2=64 => sum<3e-7 */

// ---------------- kernel 1: FWHT + fp8-e4m3 quantize, fragment-ordered Qf8 -------
// Exact Sylvester WHT over 512; rows of H/sqrt(512) orthonormal => Parseval:
// d_proj <= d_true. fp8 e4m3 halves filter operand bytes vs bf16 (same MFMA
// rate). Layout: byte(row,c,kg) = (row>>4)*2048 + c*512 + kg*128 + (row&15)*8,
// so filter lane L reads 8B at blk*2048 + c*512 + L*8 — fully coalesced.
__global__ __launch_bounds__(256) void prep_kernel(const float* __restrict__ lbl,
                                                   const float* __restrict__ pred,
                                                   unsigned char* __restrict__ Qf8,
                                                   float* __restrict__ xnorm,
                                                   float* __restrict__ pnorm) {
    const int w = threadIdx.x >> 6;
    const int l = threadIdx.x & 63;
    const int row = blockIdx.x * 4 + w;
    const float* src = (row < NROWS) ? (lbl + (size_t)row * DIM)
                                     : (pred + (size_t)(row - NROWS) * DIM);
    const float4 v0 = *(const float4*)(src + l * 8);
    const float4 v1 = *(const float4*)(src + l * 8 + 4);
    float h[8] = {v0.x, v0.y, v0.z, v0.w, v1.x, v1.y, v1.z, v1.w};

    float nrm = 0.f;  // exact f32 norm of the ORIGINAL row (fallback uses it)
#pragma unroll
    for (int j = 0; j < 8; ++j) nrm += h[j] * h[j];
#pragma unroll
    for (int off = 32; off; off >>= 1) nrm += __shfl_xor(nrm, off);
    if (l == 0) xnorm[row] = nrm;

#define BFLY(a, b) { float t = h[a]; h[a] = t + h[b]; h[b] = t - h[b]; }
    BFLY(0, 1) BFLY(2, 3) BFLY(4, 5) BFLY(6, 7)
    BFLY(0, 2) BFLY(1, 3) BFLY(4, 6) BFLY(5, 7)
    BFLY(0, 4) BFLY(1, 5) BFLY(2, 6) BFLY(3, 7)
#undef BFLY
#pragma unroll
    for (int m = 1; m <= 32; m <<= 1) {
#pragma unroll
        for (int j = 0; j < 8; ++j) {
            float p = __shfl_xor(h[j], m);
            h[j] = (l & m) ? (p - h[j]) : (h[j] + p);
        }
    }
    // scale by 1/sqrt(512); pack 8 coefs -> 2x4 fp8; pnorm from DEQUANTIZED values
#pragma unroll
    for (int j = 0; j < 8; ++j) h[j] *= 0.04419417382f;
    uint32_t lo = 0, hi = 0;
    lo = __builtin_amdgcn_cvt_pk_fp8_f32(h[0], h[1], lo, false);
    lo = __builtin_amdgcn_cvt_pk_fp8_f32(h[2], h[3], lo, true);
    hi = __builtin_amdgcn_cvt_pk_fp8_f32(h[4], h[5], hi, false);
    hi = __builtin_amdgcn_cvt_pk_fp8_f32(h[6], h[7], hi, true);
    float s = 0.f, b0, b1;  // selector must be a LITERAL (frontend constraint)
    b0 = __builtin_amdgcn_cvt_f32_fp8(lo, 0); b1 = __builtin_amdgcn_cvt_f32_fp8(hi, 0);
    s += b0 * b0 + b1 * b1;
    b0 = __builtin_amdgcn_cvt_f32_fp8(lo, 1); b1 = __builtin_amdgcn_cvt_f32_fp8(hi, 1);
    s += b0 * b0 + b1 * b1;
    b0 = __builtin_amdgcn_cvt_f32_fp8(lo, 2); b1 = __builtin_amdgcn_cvt_f32_fp8(hi, 2);
    s += b0 * b0 + b1 * b1;
    b0 = __builtin_amdgcn_cvt_f32_fp8(lo, 3); b1 = __builtin_amdgcn_cvt_f32_fp8(hi, 3);
    s += b0 * b0 + b1 * b1;
    if (l < 16) {
        const size_t off8 = (size_t)(row >> 4) * 2048 + (l >> 2) * 512 + (l & 3) * 128 + (row & 15) * 8;
        *(uint2*)(Qf8 + off8) = make_uint2(lo, hi);
    }
    s = (l < 16) ? s : 0.f;
#pragma unroll
    for (int off = 32; off; off >>= 1) s += __shfl_xor(s, off);
    if (l == 0) pnorm[row] = s;
}

// ---------------- kernel 2: fp8 certify filter, XCD-LOCAL triangle partition -----
// r20 body; ONLY the tile->XCD mapping changed (single variable). XCD x owns
// bn-bands {4x..4x+3} U {60-4x..63-4x} — exactly 260 tiles (16x+10 + 250-16x),
// balanced by construction. Per-XCD working set: 8 B-panels (128 KB) + <=64
// A-panels (1 MB) -> L2-RESIDENT per XCD; cross-XCD/L3 panel traffic ~66->10 MB.
// Each XCD: 128 blocks x 2 tiles; local blocks 0..3 take one 260th-tile extra.
__global__ __launch_bounds__(256) void mmd_filter_kernel(const unsigned char* __restrict__ Qf8,
                                                         const float* __restrict__ pnorm,
                                                         const float* __restrict__ lbl,
                                                         const float* __restrict__ pred,
                                                         const float* __restrict__ xnorm,
                                                         float* __restrict__ partials) {
    __shared__ float red[4];

    const int bid0 = (int)blockIdx.x;
    const int x = bid0 & 7;        // XCD (dispatch round-robins blockIdx across XCDs)
    const int local = bid0 >> 3;   // 0..127 within XCD
    const int phys = x * (GRID4 / 8) + local;  // partials slot
    const int tid = threadIdx.x;
    const int wv = tid >> 6;
    const int l = tid & 63;
    const int wm = wv >> 1, wn = wv & 1;
    const int rl = l & 15;

    // decode local tile index t (0..259) within XCD x's band-pair
    auto DECX = [&](int t, int& bm, int& bn) {
#pragma unroll
        for (int q = 0; q < 8; ++q) {
            const int cand = (q < 4) ? (4 * x + q) : (60 - 4 * x + (q - 4));
            if (t <= cand) { bn = cand; bm = t; return; }
            t -= cand + 1;
        }
        bm = 0; bn = 4 * x;  // unreachable
    };
    int bm0, bn0, bm1, bn1, bm2 = 0, bn2 = 0;
    DECX(2 * local, bm0, bn0);
    DECX(2 * local + 1, bm1, bn1);
    const int nT = (local < 4) ? 3 : 2;  // 256+local covers tiles 256..259
    if (nT == 3) DECX(256 + local, bm2, bn2);

    auto baseof = [&](int rowblk) {
        return (const char*)Qf8 + (size_t)(rowblk >> 4) * 2048 + (size_t)l * 8;
    };

    f32x4 acc[4][4];
#pragma unroll
    for (int m = 0; m < 4; ++m)
#pragma unroll
        for (int n = 0; n < 4; ++n) acc[m][n] = (f32x4){0.f, 0.f, 0.f, 0.f};

    long aE[4], bE[4], aO[4], bO[4];
    const char* bA = baseof(bm0 * 128 + wm * 64);
    const char* bB = baseof(bn0 * 128 + wn * 64);

#define LDX(a, b, kc, pA, pB)                                       \
    {                                                               \
        _Pragma("unroll") for (int m = 0; m < 4; ++m) {             \
            a[m] = *(const long*)((pA) + m * 2048 + (kc) * 512);    \
            b[m] = *(const long*)((pB) + m * 2048 + (kc) * 512);    \
        }                                                           \
    }
#define MMX(a, b)                                                   \
    {                                                               \
        _Pragma("unroll") for (int m = 0; m < 4; ++m)               \
            _Pragma("unroll") for (int n = 0; n < 4; ++n)           \
                acc[m][n] = __builtin_amdgcn_mfma_f32_16x16x32_fp8_fp8(a[m], b[n], acc[m][n], 0, 0, 0); \
    }

    LDX(aE, bE, 0, bA, bB);
    float grand = 0.f;

#pragma unroll 1
    for (int k = 0; k < nT; ++k) {
        const int bmT = (k == 0) ? bm0 : ((k == 1) ? bm1 : bm2);
        const int bnT = (k == 0) ? bn0 : ((k == 1) ? bn1 : bn2);
        const int rowA = bmT * 128 + wm * 64;
        const int rowB = bnT * 128 + wn * 64;

        LDX(aO, bO, 1, bA, bB); MMX(aE, bE);
        LDX(aE, bE, 2, bA, bB); MMX(aO, bO);
        LDX(aO, bO, 3, bA, bB); MMX(aE, bE);

        if (k + 1 < nT) {  // prefetch next tile's chunk 0 into freed even regs
            const int bmN = (k == 0) ? bm1 : bm2;
            const int bnN = (k == 0) ? bn1 : bn2;
            bA = baseof(bmN * 128 + wm * 64);
            bB = baseof(bnN * 128 + wn * 64);
            LDX(aE, bE, 0, bA, bB);
        }
        MMX(aO, bO);

        // ---- epilogue (register-only; certify-skip + rare exact fallback) ----
        float pj[4];
        float4 piv[4];
#pragma unroll
        for (int n = 0; n < 4; ++n) pj[n] = pnorm[rowB + n * 16 + rl];
#pragma unroll
        for (int m = 0; m < 4; ++m)
            piv[m] = *(const float4*)(pnorm + rowA + m * 16 + (l >> 4) * 4);

        float tmin = 1e30f;  // min fragment distance (i==j excluded)
#pragma unroll
        for (int m = 0; m < 4; ++m)
#pragma unroll
            for (int n = 0; n < 4; ++n) {
                const int i0 = rowA + m * 16 + (l >> 4) * 4;
                const int j = rowB + n * 16 + rl;
                const int delta = j - i0;
                float d0 = (piv[m].x + pj[n]) - 2.f * acc[m][n][0];
                float d1 = (piv[m].y + pj[n]) - 2.f * acc[m][n][1];
                float d2 = (piv[m].z + pj[n]) - 2.f * acc[m][n][2];
                float d3 = (piv[m].w + pj[n]) - 2.f * acc[m][n][3];
                d0 = (delta == 0) ? 1e30f : d0;
                d1 = (delta == 1) ? 1e30f : d1;
                d2 = (delta == 2) ? 1e30f : d2;
                d3 = (delta == 3) ? 1e30f : d3;
                tmin = fminf(tmin, fminf(fminf(d0, d1), fminf(d2, d3)));
            }

        if (__ballot(tmin < THR)) {  // rare (~9 pairs expected); wave-uniform
            float local_s = 0.f;
#pragma unroll
            for (int m = 0; m < 4; ++m)
#pragma unroll
                for (int n = 0; n < 4; ++n) {
                    float d[4];
                    d[0] = (piv[m].x + pj[n]) - 2.f * acc[m][n][0];
                    d[1] = (piv[m].y + pj[n]) - 2.f * acc[m][n][1];
                    d[2] = (piv[m].z + pj[n]) - 2.f * acc[m][n][2];
                    d[3] = (piv[m].w + pj[n]) - 2.f * acc[m][n][3];
                    const int i0 = rowA + m * 16 + (l >> 4) * 4;
                    const int j = rowB + n * 16 + rl;
#pragma unroll
                    for (int r = 0; r < 4; ++r) {
                        unsigned long long bal = __ballot((d[r] < THR) && (i0 + r != j));
                        while (bal) {  // wave-cooperative exact f32 term
                            const int src = __ffsll((long long)bal) - 1;
                            bal &= bal - 1;
                            const int ii = __shfl(i0 + r, src);
                            const int jj = __shfl(j, src);
                            const float* ri = (ii < NROWS) ? lbl + (size_t)ii * DIM
                                                           : pred + (size_t)(ii - NROWS) * DIM;
                            const float* rj = (jj < NROWS) ? lbl + (size_t)jj * DIM
                                                           : pred + (size_t)(jj - NROWS) * DIM;
                            const float4 a0 = *(const float4*)(ri + l * 8);
                            const float4 a1 = *(const float4*)(ri + l * 8 + 4);
                            const float4 c0 = *(const float4*)(rj + l * 8);
                            const float4 c1 = *(const float4*)(rj + l * 8 + 4);
                            float p = a0.x * c0.x + a0.y * c0.y + a0.z * c0.z + a0.w * c0.w +
                                      a1.x * c1.x + a1.y * c1.y + a1.z * c1.z + a1.w * c1.w;
#pragma unroll
                            for (int off = 32; off; off >>= 1) p += __shfl_xor(p, off);
                            if (l == src) {
                                float dt = xnorm[ii] + xnorm[jj] - 2.f * p;
                                local_s += exp2f(-0.72134752f * dt);
                            }
                        }
                    }
                }
            const float sgn = ((bmT < 32) == (bnT < 32)) ? 1.f : -1.f;
            grand += local_s * sgn * ((bmT == bnT) ? 1.f : 2.f);
        }
#pragma unroll
        for (int m = 0; m < 4; ++m)
#pragma unroll
            for (int n = 0; n < 4; ++n) acc[m][n] = (f32x4){0.f, 0.f, 0.f, 0.f};
    }
#undef LDX
#undef MMX

    // ---- block reduce (plain store; separate reduce kernel — r18's lesson) ----
#pragma unroll
    for (int off = 32; off; off >>= 1) grand += __shfl_xor(grand, off);
    if (l == 0) red[wv] = grand;
    __syncthreads();
    if (tid == 0) partials[phys] = red[0] + red[1] + red[2] + red[3];
}

// ---------------- kernel 3: deterministic final reduce ---------------------------
__global__ __launch_bounds__(256) void reduce_kernel(const float* __restrict__ partials,
                                                     float* __restrict__ out, int n) {
    __shared__ float red[4];
    float s = 0.f;
    for (int i = threadIdx.x; i < n; i += 256) s += partials[i];
#pragma unroll
    for (int off = 32; off; off >>= 1) s += __shfl_xor(s, off);
    if ((threadIdx.x & 63) == 0) red[threadIdx.x >> 6] = s;
    __syncthreads();
    if (threadIdx.x == 0)  // + 8192 = the Z-diagonal (exp(0)=1, sign +1, exact)
        out[0] = (red[0] + red[1] + red[2] + red[3] + 8192.f) * (1.f / 16777216.f);
}

extern "C" void kernel_launch(void* const* d_in, const int* in_sizes, int n_in,
                              void* d_out, int out_size, void* d_ws, size_t ws_size,
                              hipStream_t stream) {
    const float* lbl = (const float*)d_in[0];
    const float* pred = (const float*)d_in[1];
    unsigned char* Qf8 = (unsigned char*)d_ws;                        // 1 MiB
    float* xnorm = (float*)((char*)d_ws + (size_t)ZROWS * DIMP);      // 32 KiB
    float* pnorm = xnorm + ZROWS;                                     // 32 KiB
    float* partials = pnorm + ZROWS;                                  // 4 KiB

    prep_kernel<<<ZROWS / 4, 256, 0, stream>>>(lbl, pred, Qf8, xnorm, pnorm);
    mmd_filter_kernel<<<GRID4, 256, 0, stream>>>(Qf8, pnorm, lbl, pred, xnorm, partials);
    reduce_kernel<<<1, 256, 0, stream>>>(partials, (float*)d_out, GRID4);
}